// Round 13
// baseline (348.035 us; speedup 1.0000x reference)
//
#include <hip/hip_runtime.h>
#include <math.h>

#define D 256
#define CLS 10
#define BLOCK 256
#define NWAVE 4            // 256 threads / 64 lanes
#define PSTRIDE 516        // 512 class-sum floats + cnt8 + cnt9 + intra (+1 pad)
#define MAIN_BLOCKS 2048
#define RED_BLOCKS 64
#define GRP 32             // blocks per reduction group (MAIN_BLOCKS/RED_BLOCKS)

// v += dpp_move(v, ctrl); invalid source lanes contribute 0 (bound_ctrl=1).
__device__ __forceinline__ float dpp_add(float v, const int ctrl) {
    int moved;
    switch (ctrl) {
        case 0x111: moved = __builtin_amdgcn_update_dpp(0, __float_as_int(v), 0x111, 0xf, 0xf, true); break;
        case 0x112: moved = __builtin_amdgcn_update_dpp(0, __float_as_int(v), 0x112, 0xf, 0xf, true); break;
        case 0x114: moved = __builtin_amdgcn_update_dpp(0, __float_as_int(v), 0x114, 0xf, 0xf, true); break;
        case 0x118: moved = __builtin_amdgcn_update_dpp(0, __float_as_int(v), 0x118, 0xf, 0xf, true); break;
        case 0x142: moved = __builtin_amdgcn_update_dpp(0, __float_as_int(v), 0x142, 0xf, 0xf, true); break;
        default:    moved = __builtin_amdgcn_update_dpp(0, __float_as_int(v), 0x143, 0xf, 0xf, true); break;
    }
    return v + __int_as_float(moved);
}

// Full 64-lane sum; result valid in lane 63. 6 VALU ops, 0 DS ops.
__device__ __forceinline__ float wave_sum63(float v) {
    v = dpp_add(v, 0x111);   // row_shr:1
    v = dpp_add(v, 0x112);   // row_shr:2
    v = dpp_add(v, 0x114);   // row_shr:4
    v = dpp_add(v, 0x118);   // row_shr:8
    v = dpp_add(v, 0x142);   // row_bcast15
    v = dpp_add(v, 0x143);   // row_bcast31 -> lane63 holds full sum
    return v;
}

// The R2 (89us) per-row body, verbatim.
#define PROCESS(LBL, F)                                                         \
    {                                                                           \
        const float4 c = *(const float4*)(s_center + (LBL) * D + (lane << 2));  \
        float tx = fmaf(-2.f, c.x, (F).x);                                      \
        float ty = fmaf(-2.f, c.y, (F).y);                                      \
        float tz = fmaf(-2.f, c.z, (F).z);                                      \
        float tw = fmaf(-2.f, c.w, (F).w);                                      \
        float val = (F).x * tx;                                                 \
        val = fmaf((F).y, ty, val);                                             \
        val = fmaf((F).z, tz, val);                                             \
        val = fmaf((F).w, tw, val);                                             \
        const float s = wave_sum63(val);                                        \
        if (lane == 63) {                                                       \
            float d2 = fmaxf(s + s_cnorm[(LBL)], 0.f);                          \
            float own = fminf(fmaxf(sqrtf(d2), 1e-16f), 1e16f);                 \
            intra += own;                                                       \
            cnt8 += ((LBL) == CLS - 2) ? 1.f : 0.f;                             \
            cnt9 += ((LBL) == CLS - 1) ? 1.f : 0.f;                             \
        }                                                                       \
        if ((LBL) == CLS - 2) { a8x += (F).x; a8y += (F).y; a8z += (F).z; a8w += (F).w; } \
        if ((LBL) == CLS - 1) { a9x += (F).x; a9y += (F).y; a9z += (F).z; a9w += (F).w; } \
    }

// Shared main-phase body (R10's loss_main streaming pass, verbatim).
#define MAIN_BODY(PARTIALS_PTR)                                                     \
    __shared__ __align__(16) float s_center[CLS * D];                               \
    __shared__ float s_cnorm[CLS];                                                  \
    __shared__ float s_acc[NWAVE][2 * D];                                           \
    __shared__ float s_scal[NWAVE][3];                                              \
    for (int i = threadIdx.x; i < CLS * D; i += BLOCK) s_center[i] = center[i];     \
    __syncthreads();                                                                \
    if (threadIdx.x < CLS) {                                                        \
        float s = 0.f;                                                              \
        _Pragma("unroll 8")                                                         \
        for (int d = 0; d < D; ++d) {                                               \
            float v = s_center[threadIdx.x * D + d];                                \
            s = fmaf(v, v, s);                                                      \
        }                                                                           \
        s_cnorm[threadIdx.x] = s;                                                   \
    }                                                                               \
    __syncthreads();                                                                \
    const int wave = threadIdx.x >> 6;                                              \
    const int lane = threadIdx.x & 63;                                              \
    const int gw = blockIdx.x * NWAVE + wave;                                       \
    const int nw = nblocks * NWAVE;                                                 \
    float intra = 0.f, cnt8 = 0.f, cnt9 = 0.f;                                      \
    float a8x = 0.f, a8y = 0.f, a8z = 0.f, a8w = 0.f;                               \
    float a9x = 0.f, a9y = 0.f, a9z = 0.f, a9w = 0.f;                               \
    int r = gw;                                                                     \
    const bool v0 = r < nrows;                                                      \
    const bool v1 = r + nw < nrows;                                                 \
    int l0 = 0, l1 = 0;                                                             \
    float4 f0 = make_float4(0.f, 0.f, 0.f, 0.f), f1 = f0;                           \
    if (v0) {                                                                       \
        l0 = labels[r];                                                             \
        f0 = *(const float4*)(feat + (size_t)r * D + (lane << 2));                  \
    }                                                                               \
    if (v1) {                                                                       \
        l1 = labels[r + nw];                                                        \
        f1 = *(const float4*)(feat + ((size_t)r + nw) * D + (lane << 2));           \
    }                                                                               \
    while (r + 2 * nw < nrows) {                                                    \
        const int l2 = labels[r + 2 * nw];                                          \
        const float4 f2 = *(const float4*)(feat + ((size_t)r + 2 * nw) * D + (lane << 2)); \
        PROCESS(l0, f0);                                                            \
        l0 = l1; f0 = f1;                                                           \
        l1 = l2; f1 = f2;                                                           \
        r += nw;                                                                    \
    }                                                                               \
    if (v0) PROCESS(l0, f0);                                                        \
    if (v1) PROCESS(l1, f1);                                                        \
    const int e = lane << 2;                                                        \
    s_acc[wave][e + 0] = a8x;                                                       \
    s_acc[wave][e + 1] = a8y;                                                       \
    s_acc[wave][e + 2] = a8z;                                                       \
    s_acc[wave][e + 3] = a8w;                                                       \
    s_acc[wave][D + e + 0] = a9x;                                                   \
    s_acc[wave][D + e + 1] = a9y;                                                   \
    s_acc[wave][D + e + 2] = a9z;                                                   \
    s_acc[wave][D + e + 3] = a9w;                                                   \
    if (lane == 63) {                                                               \
        s_scal[wave][0] = cnt8;                                                     \
        s_scal[wave][1] = cnt9;                                                     \
        s_scal[wave][2] = intra;                                                    \
    }                                                                               \
    __syncthreads();                                                                \
    float* po = (PARTIALS_PTR) + (size_t)blockIdx.x * PSTRIDE;                      \
    for (int i = threadIdx.x; i < 2 * D; i += BLOCK)                                \
        po[i] = s_acc[0][i] + s_acc[1][i] + s_acc[2][i] + s_acc[3][i];              \
    if (threadIdx.x < 3)                                                            \
        po[2 * D + threadIdx.x] = s_scal[0][threadIdx.x] + s_scal[1][threadIdx.x]   \
                                + s_scal[2][threadIdx.x] + s_scal[3][threadIdx.x];

// ============ Fused single-pass kernel (hierarchical last-block) ============
// Main phase (byte-equal R10 body) -> group ticket -> 64 group leaders reduce
// 32 rows each -> leader ticket -> last leader finalizes. No spinning, no
// grid sync; fence+ticket pattern validated in R4/R5/R12 tails.
__global__ __launch_bounds__(BLOCK) void loss_fused(
    const float* __restrict__ feat, const int* __restrict__ labels,
    const float* __restrict__ center, float* __restrict__ partials,
    float* __restrict__ partials2, unsigned* __restrict__ tickets,
    float* __restrict__ out, int nrows, int nblocks)
{
    MAIN_BODY(partials)

    // ---- group ticket: last block of each 32-block group becomes leader ----
    __threadfence();                      // release partials stores
    __syncthreads();
    __shared__ unsigned oldv;
    const int g = blockIdx.x >> 5;        // group id, 64 groups
    if (threadIdx.x == 0) oldv = atomicAdd(&tickets[g], 1u);
    __syncthreads();
    if (oldv != GRP - 1) return;
    __threadfence();                      // acquire group's partials

    // ---- group-leader reduce: 32 rows -> partials2[g] (fixed order) ----
    const int t = threadIdx.x;
    {
        float s0 = 0.f, s1 = 0.f, sc = 0.f;
        const float* gp = partials + (size_t)(g << 5) * PSTRIDE;
        #pragma unroll 8
        for (int i = 0; i < GRP; ++i) {
            const float* p = gp + (size_t)i * PSTRIDE;
            s0 += p[t];
            s1 += p[D + t];
            if (t < 3) sc += p[2 * D + t];
        }
        float* o = partials2 + (size_t)g * PSTRIDE;
        o[t] = s0;
        o[D + t] = s1;
        if (t < 3) o[2 * D + t] = sc;
    }

    // ---- leader ticket: last of 64 leaders becomes finalizer ----
    __threadfence();
    __syncthreads();
    if (threadIdx.x == 0) oldv = atomicAdd(&tickets[RED_BLOCKS], 1u);
    __syncthreads();
    if (oldv != RED_BLOCKS - 1) return;
    __threadfence();                      // acquire all partials2

    // ---- final combine (fixed order, fp64) + outputs ----
    double s8 = 0.0, s9 = 0.0;
    #pragma unroll 8
    for (int rr = 0; rr < RED_BLOCKS; ++rr) {
        const float* p = partials2 + (size_t)rr * PSTRIDE;
        s8 += (double)p[t];
        s9 += (double)p[D + t];
    }
    __shared__ double sh[3];
    if (t < 3) {
        double s = 0.0;
        #pragma unroll 8
        for (int rr = 0; rr < RED_BLOCKS; ++rr)
            s += (double)partials2[(size_t)rr * PSTRIDE + 2 * D + t];
        sh[t] = s;
    }
    __shared__ double ssq[BLOCK];
    __syncthreads();

    const double cnt8d = fmax(sh[0], 1.0);
    const double cnt9d = fmax(sh[1], 1.0);
    const double c8 = ((double)center[(CLS - 2) * D + t] + s8) / cnt8d;
    const double c9 = ((double)center[(CLS - 1) * D + t] + s9) / cnt9d;
    const double diff = c8 - c9;
    ssq[t] = diff * diff;
    __syncthreads();

    for (int s = BLOCK / 2; s > 0; s >>= 1) {
        if (t < s) ssq[t] += ssq[t + s];
        __syncthreads();
    }

    if (t == 0) {
        const double last = sqrt(fmax(ssq[0], 0.0));
        const double denom = fmin(fmax(2.0 * last, 1e-16), 1e16);
        out[0] = (float)(sh[2] / (double)nrows);
        out[1] = (float)(1.0 / denom);
    }
    for (int i = t; i < CLS * D; i += BLOCK) out[2 + i] = center[i];
}

// ================= Generic 3-kernel fallback (nblocks != 2048) =================
__global__ __launch_bounds__(BLOCK) void loss_main_basic(
    const float* __restrict__ feat, const int* __restrict__ labels,
    const float* __restrict__ center, float* __restrict__ partials,
    int nrows, int nblocks)
{
    MAIN_BODY(partials)
}

__global__ __launch_bounds__(BLOCK) void loss_reduce(
    const float* __restrict__ partials, float* __restrict__ out2, int nblocks)
{
    const int t = threadIdx.x;
    float s0 = 0.f, s1 = 0.f, sc = 0.f;
    for (int r = blockIdx.x; r < nblocks; r += gridDim.x) {
        const float* p = partials + (size_t)r * PSTRIDE;
        s0 += p[t];
        s1 += p[D + t];
        if (t < 3) sc += p[2 * D + t];
    }
    float* o = out2 + (size_t)blockIdx.x * PSTRIDE;
    o[t] = s0;
    o[D + t] = s1;
    if (t < 3) o[2 * D + t] = sc;
}

__global__ __launch_bounds__(BLOCK) void loss_final(
    const float* __restrict__ partials2, const float* __restrict__ center,
    float* __restrict__ out, int nrows)
{
    const int t = threadIdx.x;
    double s8 = 0.0, s9 = 0.0;
    #pragma unroll 16
    for (int r = 0; r < RED_BLOCKS; ++r) {
        const float* p = partials2 + (size_t)r * PSTRIDE;
        s8 += (double)p[t];
        s9 += (double)p[D + t];
    }
    __shared__ double sh[3];
    if (t < 3) {
        double s = 0.0;
        #pragma unroll 16
        for (int r = 0; r < RED_BLOCKS; ++r)
            s += (double)partials2[(size_t)r * PSTRIDE + 2 * D + t];
        sh[t] = s;
    }
    __shared__ double ssq[BLOCK];
    __syncthreads();

    const double cnt8 = fmax(sh[0], 1.0);
    const double cnt9 = fmax(sh[1], 1.0);
    const double c8 = ((double)center[(CLS - 2) * D + t] + s8) / cnt8;
    const double c9 = ((double)center[(CLS - 1) * D + t] + s9) / cnt9;
    const double diff = c8 - c9;
    ssq[t] = diff * diff;
    __syncthreads();

    for (int s = BLOCK / 2; s > 0; s >>= 1) {
        if (t < s) ssq[t] += ssq[t + s];
        __syncthreads();
    }

    if (t == 0) {
        const double last = sqrt(fmax(ssq[0], 0.0));
        const double denom = fmin(fmax(2.0 * last, 1e-16), 1e16);
        out[0] = (float)(sh[2] / (double)nrows);
        out[1] = (float)(1.0 / denom);
    }
    for (int i = t; i < CLS * D; i += BLOCK) out[2 + i] = center[i];
}

extern "C" void kernel_launch(void* const* d_in, const int* in_sizes, int n_in,
                              void* d_out, int out_size, void* d_ws, size_t ws_size,
                              hipStream_t stream) {
    const float* feat   = (const float*)d_in[0];
    const int*   labels = (const int*)d_in[1];
    const float* center = (const float*)d_in[2];
    float* out = (float*)d_out;

    const int nrows = in_sizes[0] / D;

    int nblocks = MAIN_BLOCKS;
    while (nblocks > 64 &&
           ((size_t)nblocks + RED_BLOCKS + 2) * PSTRIDE * sizeof(float) > ws_size)
        nblocks >>= 1;

    float* partials  = (float*)d_ws;
    float* partials2 = partials + (size_t)nblocks * PSTRIDE;
    unsigned* tickets = (unsigned*)(partials2 + (size_t)RED_BLOCKS * PSTRIDE);

    if (nblocks == MAIN_BLOCKS) {
        // zero 64 group tickets + 1 leader ticket (poisoned ws, never re-poisoned)
        hipMemsetAsync(tickets, 0, (RED_BLOCKS + 1) * sizeof(unsigned), stream);
        loss_fused<<<MAIN_BLOCKS, BLOCK, 0, stream>>>(
            feat, labels, center, partials, partials2, tickets, out, nrows, MAIN_BLOCKS);
    } else {
        loss_main_basic<<<nblocks, BLOCK, 0, stream>>>(feat, labels, center,
                                                       partials, nrows, nblocks);
        loss_reduce<<<RED_BLOCKS, BLOCK, 0, stream>>>(partials, partials2, nblocks);
        loss_final<<<1, BLOCK, 0, stream>>>(partials2, center, out, nrows);
    }
}

// Round 14
// 69.913 us; speedup vs baseline: 4.9781x; 4.9781x over previous
//
#include <hip/hip_runtime.h>
#include <math.h>

#define D 256
#define CLS 10
#define BLOCK 256
#define NWAVE 4            // 256 threads / 64 lanes
#define PSTRIDE 516        // 512 class-sum floats + cnt8 + cnt9 + intra (+1 pad)
#define MAIN_BLOCKS 2048
#define RED_BLOCKS 64

// v += dpp_move(v, ctrl); invalid source lanes contribute 0 (bound_ctrl=1).
__device__ __forceinline__ float dpp_add(float v, const int ctrl) {
    int moved;
    switch (ctrl) {
        case 0x111: moved = __builtin_amdgcn_update_dpp(0, __float_as_int(v), 0x111, 0xf, 0xf, true); break;
        case 0x112: moved = __builtin_amdgcn_update_dpp(0, __float_as_int(v), 0x112, 0xf, 0xf, true); break;
        case 0x114: moved = __builtin_amdgcn_update_dpp(0, __float_as_int(v), 0x114, 0xf, 0xf, true); break;
        case 0x118: moved = __builtin_amdgcn_update_dpp(0, __float_as_int(v), 0x118, 0xf, 0xf, true); break;
        case 0x142: moved = __builtin_amdgcn_update_dpp(0, __float_as_int(v), 0x142, 0xf, 0xf, true); break;
        default:    moved = __builtin_amdgcn_update_dpp(0, __float_as_int(v), 0x143, 0xf, 0xf, true); break;
    }
    return v + __int_as_float(moved);
}

// Full 64-lane sum; result valid in lane 63. 6 VALU ops, 0 DS ops.
__device__ __forceinline__ float wave_sum63(float v) {
    v = dpp_add(v, 0x111);   // row_shr:1
    v = dpp_add(v, 0x112);   // row_shr:2
    v = dpp_add(v, 0x114);   // row_shr:4
    v = dpp_add(v, 0x118);   // row_shr:8
    v = dpp_add(v, 0x142);   // row_bcast15
    v = dpp_add(v, 0x143);   // row_bcast31 -> lane63 holds full sum
    return v;
}

// The R2 (89us) per-row body, verbatim.
#define PROCESS(LBL, F)                                                         \
    {                                                                           \
        const float4 c = *(const float4*)(s_center + (LBL) * D + (lane << 2));  \
        float tx = fmaf(-2.f, c.x, (F).x);                                      \
        float ty = fmaf(-2.f, c.y, (F).y);                                      \
        float tz = fmaf(-2.f, c.z, (F).z);                                      \
        float tw = fmaf(-2.f, c.w, (F).w);                                      \
        float val = (F).x * tx;                                                 \
        val = fmaf((F).y, ty, val);                                             \
        val = fmaf((F).z, tz, val);                                             \
        val = fmaf((F).w, tw, val);                                             \
        const float s = wave_sum63(val);                                        \
        if (lane == 63) {                                                       \
            float d2 = fmaxf(s + s_cnorm[(LBL)], 0.f);                          \
            float own = fminf(fmaxf(sqrtf(d2), 1e-16f), 1e16f);                 \
            intra += own;                                                       \
            cnt8 += ((LBL) == CLS - 2) ? 1.f : 0.f;                             \
            cnt9 += ((LBL) == CLS - 1) ? 1.f : 0.f;                             \
        }                                                                       \
        if ((LBL) == CLS - 2) { a8x += (F).x; a8y += (F).y; a8z += (F).z; a8w += (F).w; } \
        if ((LBL) == CLS - 1) { a9x += (F).x; a9y += (F).y; a9z += (F).z; a9w += (F).w; } \
    }

// ---------------- Kernel 1: streaming pass over features ----------------
// BYTE-IDENTICAL to round 8/10 (70 us best). NO fences/atomics in here —
// R13 proved device-scope coherency ops collapse the stream to 0.3 TB/s.
__global__ __launch_bounds__(BLOCK) void loss_main(
    const float* __restrict__ feat, const int* __restrict__ labels,
    const float* __restrict__ center, float* __restrict__ partials,
    int nrows, int nblocks)
{
    __shared__ __align__(16) float s_center[CLS * D];   // 10 KiB
    __shared__ float s_cnorm[CLS];
    __shared__ float s_acc[NWAVE][2 * D];               // 8 KiB
    __shared__ float s_scal[NWAVE][3];

    for (int i = threadIdx.x; i < CLS * D; i += BLOCK) s_center[i] = center[i];
    __syncthreads();
    if (threadIdx.x < CLS) {
        float s = 0.f;
        #pragma unroll 8
        for (int d = 0; d < D; ++d) {
            float v = s_center[threadIdx.x * D + d];
            s = fmaf(v, v, s);
        }
        s_cnorm[threadIdx.x] = s;
    }
    __syncthreads();

    const int wave = threadIdx.x >> 6;
    const int lane = threadIdx.x & 63;
    const int gw = blockIdx.x * NWAVE + wave;
    const int nw = nblocks * NWAVE;

    float intra = 0.f, cnt8 = 0.f, cnt9 = 0.f;
    float a8x = 0.f, a8y = 0.f, a8z = 0.f, a8w = 0.f;
    float a9x = 0.f, a9y = 0.f, a9z = 0.f, a9w = 0.f;

    // depth-2 rotation: rows r, r+nw in flight; steady-state body unconditional
    int r = gw;
    const bool v0 = r < nrows;
    const bool v1 = r + nw < nrows;
    int l0 = 0, l1 = 0;
    float4 f0 = make_float4(0.f, 0.f, 0.f, 0.f), f1 = f0;
    if (v0) {
        l0 = labels[r];
        f0 = *(const float4*)(feat + (size_t)r * D + (lane << 2));
    }
    if (v1) {
        l1 = labels[r + nw];
        f1 = *(const float4*)(feat + ((size_t)r + nw) * D + (lane << 2));
    }

    while (r + 2 * nw < nrows) {
        const int l2 = labels[r + 2 * nw];
        const float4 f2 = *(const float4*)(feat + ((size_t)r + 2 * nw) * D + (lane << 2));

        PROCESS(l0, f0);

        l0 = l1; f0 = f1;
        l1 = l2; f1 = f2;
        r += nw;
    }
    if (v0) PROCESS(l0, f0);
    if (v1) PROCESS(l1, f1);

    const int e = lane << 2;
    s_acc[wave][e + 0] = a8x;
    s_acc[wave][e + 1] = a8y;
    s_acc[wave][e + 2] = a8z;
    s_acc[wave][e + 3] = a8w;
    s_acc[wave][D + e + 0] = a9x;
    s_acc[wave][D + e + 1] = a9y;
    s_acc[wave][D + e + 2] = a9z;
    s_acc[wave][D + e + 3] = a9w;
    if (lane == 63) {
        s_scal[wave][0] = cnt8;
        s_scal[wave][1] = cnt9;
        s_scal[wave][2] = intra;
    }
    __syncthreads();

    float* po = partials + (size_t)blockIdx.x * PSTRIDE;
    for (int i = threadIdx.x; i < 2 * D; i += BLOCK)
        po[i] = s_acc[0][i] + s_acc[1][i] + s_acc[2][i] + s_acc[3][i];
    if (threadIdx.x < 3)
        po[2 * D + threadIdx.x] = s_scal[0][threadIdx.x] + s_scal[1][threadIdx.x]
                                + s_scal[2][threadIdx.x] + s_scal[3][threadIdx.x];
}

// ------- Kernel 2 (fast path): compile-time trip count + unroll 16 -------
__global__ __launch_bounds__(BLOCK) void loss_reduce_fast(
    const float* __restrict__ partials, float* __restrict__ out2)
{
    const int t = threadIdx.x;
    float s0 = 0.f, s1 = 0.f, sc = 0.f;
    #pragma unroll 16
    for (int i = 0; i < MAIN_BLOCKS / RED_BLOCKS; ++i) {
        const float* p = partials + (size_t)(blockIdx.x + i * RED_BLOCKS) * PSTRIDE;
        s0 += p[t];
        s1 += p[D + t];
        if (t < 3) sc += p[2 * D + t];
    }
    float* o = out2 + (size_t)blockIdx.x * PSTRIDE;
    o[t] = s0;
    o[D + t] = s1;
    if (t < 3) o[2 * D + t] = sc;
}

// ------- Kernel 2 (generic fallback, nblocks != MAIN_BLOCKS) -------
__global__ __launch_bounds__(BLOCK) void loss_reduce(
    const float* __restrict__ partials, float* __restrict__ out2, int nblocks)
{
    const int t = threadIdx.x;
    float s0 = 0.f, s1 = 0.f, sc = 0.f;
    for (int r = blockIdx.x; r < nblocks; r += gridDim.x) {
        const float* p = partials + (size_t)r * PSTRIDE;
        s0 += p[t];
        s1 += p[D + t];
        if (t < 3) sc += p[2 * D + t];
    }
    float* o = out2 + (size_t)blockIdx.x * PSTRIDE;
    o[t] = s0;
    o[D + t] = s1;
    if (t < 3) o[2 * D + t] = sc;
}

// ---------------- Kernel 3: final combine (fp64) + center copy ----------------
__global__ __launch_bounds__(BLOCK) void loss_final(
    const float* __restrict__ partials2, const float* __restrict__ center,
    float* __restrict__ out, int nrows)
{
    const int t = threadIdx.x;
    double s8 = 0.0, s9 = 0.0;
    #pragma unroll 16
    for (int r = 0; r < RED_BLOCKS; ++r) {
        const float* p = partials2 + (size_t)r * PSTRIDE;
        s8 += (double)p[t];
        s9 += (double)p[D + t];
    }
    __shared__ double sh[3];
    if (t < 3) {
        double s = 0.0;
        #pragma unroll 16
        for (int r = 0; r < RED_BLOCKS; ++r)
            s += (double)partials2[(size_t)r * PSTRIDE + 2 * D + t];
        sh[t] = s;
    }
    __shared__ double ssq[BLOCK];
    __syncthreads();

    const double cnt8 = fmax(sh[0], 1.0);
    const double cnt9 = fmax(sh[1], 1.0);
    const double c8 = ((double)center[(CLS - 2) * D + t] + s8) / cnt8;
    const double c9 = ((double)center[(CLS - 1) * D + t] + s9) / cnt9;
    const double diff = c8 - c9;
    ssq[t] = diff * diff;
    __syncthreads();

    for (int s = BLOCK / 2; s > 0; s >>= 1) {
        if (t < s) ssq[t] += ssq[t + s];
        __syncthreads();
    }

    if (t == 0) {
        const double last = sqrt(fmax(ssq[0], 0.0));
        const double denom = fmin(fmax(2.0 * last, 1e-16), 1e16);
        out[0] = (float)(sh[2] / (double)nrows);
        out[1] = (float)(1.0 / denom);
    }
    for (int i = t; i < CLS * D; i += BLOCK) out[2 + i] = center[i];
}

extern "C" void kernel_launch(void* const* d_in, const int* in_sizes, int n_in,
                              void* d_out, int out_size, void* d_ws, size_t ws_size,
                              hipStream_t stream) {
    const float* feat   = (const float*)d_in[0];
    const int*   labels = (const int*)d_in[1];
    const float* center = (const float*)d_in[2];
    float* out = (float*)d_out;

    const int nrows = in_sizes[0] / D;

    int nblocks = MAIN_BLOCKS;
    while (nblocks > 64 &&
           ((size_t)nblocks + RED_BLOCKS) * PSTRIDE * sizeof(float) > ws_size)
        nblocks >>= 1;

    float* partials  = (float*)d_ws;
    float* partials2 = partials + (size_t)nblocks * PSTRIDE;

    loss_main<<<nblocks, BLOCK, 0, stream>>>(feat, labels, center, partials, nrows, nblocks);
    if (nblocks == MAIN_BLOCKS)
        loss_reduce_fast<<<RED_BLOCKS, BLOCK, 0, stream>>>(partials, partials2);
    else
        loss_reduce<<<RED_BLOCKS, BLOCK, 0, stream>>>(partials, partials2, nblocks);
    loss_final<<<1, BLOCK, 0, stream>>>(partials2, center, out, nrows);
}